// Round 2
// baseline (1709.511 us; speedup 1.0000x reference)
//
#include <hip/hip_runtime.h>
#include <cstdint>

// Problem constants (B,N,H,D fixed by setup_inputs)
#define BB 2
#define NN 2048
#define HH 16
#define DD 128
#define BH 32   // BB*HH
#define NPROJ 7

typedef __bf16 bf16x8 __attribute__((ext_vector_type(8)));
typedef float f32x4 __attribute__((ext_vector_type(4)));

__device__ __forceinline__ unsigned short f2bf(float f) {
  unsigned int u = __float_as_uint(f);
  u += 0x7fff + ((u >> 16) & 1);   // RN-even
  return (unsigned short)(u >> 16);
}

__device__ __forceinline__ bf16x8 load_q8(const float* p) {
  float4 a = *(const float4*)p;
  float4 b = *(const float4*)(p + 4);
  unsigned short r[8] = {f2bf(a.x), f2bf(a.y), f2bf(a.z), f2bf(a.w),
                         f2bf(b.x), f2bf(b.y), f2bf(b.z), f2bf(b.w)};
  return *(bf16x8*)r;
}

// ---------------------------------------------------------------------------
// 1) Fused: LSH hash of q and k rows (blocks < 4096) + V bf16 transpose to
//    [B,H,D,N] (blocks >= 4096). Hash: 8 lanes per row, fp64 accumulation.
// ---------------------------------------------------------------------------
__global__ void prep_kernel(const float* __restrict__ q, const float* __restrict__ k,
                            const float* __restrict__ v, const float* __restrict__ pd,
                            int* __restrict__ qh, int* __restrict__ kh,
                            unsigned short* __restrict__ Vt) {
  __shared__ __align__(16) char smem[64 * 132 * 2];  // union: spd (3.5K) / tile (16.5K)
  if (blockIdx.x < 4096) {
    float* spd = (float*)smem;
    for (int i = threadIdx.x; i < DD * NPROJ; i += 256) spd[i] = pd[i];
    __syncthreads();
    long long gid = (long long)blockIdx.x * 256 + threadIdx.x;
    int part = (int)(gid & 7);
    long long row = gid >> 3;
    const long long NR = (long long)BB * NN * HH;
    int isk = row >= NR;
    long long r = isk ? row - NR : row;            // flat [b][n][h]
    const float* src = (isk ? k : q) + r * DD + part * 16;
    double acc[NPROJ];
    for (int p = 0; p < NPROJ; ++p) acc[p] = 0.0;
    for (int d = 0; d < 16; d += 4) {
      float4 x = *(const float4*)(src + d);
      int dbase = part * 16 + d;
      for (int p = 0; p < NPROJ; ++p) {
        acc[p] += (double)x.x * (double)spd[(dbase + 0) * NPROJ + p]
                + (double)x.y * (double)spd[(dbase + 1) * NPROJ + p]
                + (double)x.z * (double)spd[(dbase + 2) * NPROJ + p]
                + (double)x.w * (double)spd[(dbase + 3) * NPROJ + p];
      }
    }
    for (int off = 1; off < 8; off <<= 1)
      for (int p = 0; p < NPROJ; ++p) acc[p] += __shfl_xor(acc[p], off);
    if (part == 0) {
      int bin = 0;
      for (int p = 0; p < NPROJ; ++p) bin |= ((int)(acc[p] > 0.0)) << p;
      int hsh = bin ^ (bin >> 1);                  // _unit_hamming == Gray code
      int b_ = (int)(r / (NN * HH));
      int rem = (int)(r % (NN * HH));
      int n_ = rem / HH, h_ = rem % HH;
      (isk ? kh : qh)[((long long)b_ * HH + h_) * NN + n_] = hsh;
    }
  } else {
    unsigned short (*tile)[132] = (unsigned short(*)[132])smem;
    int blk = blockIdx.x - 4096;
    int bh = blk >> 5;
    int n0 = (blk & 31) * 64;
    int b = bh >> 4, h = bh & 15;
    for (int it = 0; it < 8; ++it) {
      int cid = it * 256 + threadIdx.x;
      int r = cid >> 5, d4 = (cid & 31) * 4;
      float4 x = *(const float4*)(v + (((long long)(b * NN + n0 + r) * HH + h) << 7) + d4);
      *(ushort4*)&tile[r][d4] = make_ushort4(f2bf(x.x), f2bf(x.y), f2bf(x.z), f2bf(x.w));
    }
    __syncthreads();
    for (int it = 0; it < 8; ++it) {
      int cid = it * 256 + threadIdx.x;
      int d = cid >> 4, n4 = (cid & 15) * 4;
      ushort4 y = make_ushort4(tile[n4 + 0][d], tile[n4 + 1][d], tile[n4 + 2][d], tile[n4 + 3][d]);
      *(ushort4*)(Vt + ((long long)bh * DD + d) * NN + n0 + n4) = y;
    }
  }
}

// ---------------------------------------------------------------------------
// 2) Stable counting sort of q_hash per (b,h). 128 bins, 4 segments of 512.
// ---------------------------------------------------------------------------
__global__ void sort_kernel(const int* __restrict__ qh, int* __restrict__ sidx,
                            int* __restrict__ qhs) {
  __shared__ int sh[NN];
  __shared__ int cnt[4][128];
  __shared__ int cum[128];
  int bh = blockIdx.x;
  const int* src = qh + (long long)bh * NN;
  for (int i = threadIdx.x; i < NN; i += 512) sh[i] = src[i];
  __syncthreads();
  int bin = threadIdx.x & 127, seg = threadIdx.x >> 7;
  int n0 = seg * (NN / 4);
  int c = 0;
  for (int n = n0; n < n0 + NN / 4; ++n) c += (sh[n] == bin);
  cnt[seg][bin] = c;
  __syncthreads();
  if (threadIdx.x == 0) {
    int run = 0;
    for (int t = 0; t < 128; ++t) {
      cum[t] = run;
      run += cnt[0][t] + cnt[1][t] + cnt[2][t] + cnt[3][t];
    }
  }
  __syncthreads();
  int pos = cum[bin];
  for (int s = 0; s < seg; ++s) pos += cnt[s][bin];
  for (int n = n0; n < n0 + NN / 4; ++n)
    if (sh[n] == bin) {
      sidx[(long long)bh * NN + pos] = n;
      qhs[(long long)bh * NN + pos] = bin;
      ++pos;
    }
}

// ---------------------------------------------------------------------------
// 3) keep[j] = OR over flat idx [j*1024,(j+1)*1024) of (q_hash_sort == k_hash)
// ---------------------------------------------------------------------------
__global__ void keep_kernel(const int* __restrict__ qhs, const int* __restrict__ kh,
                            int* __restrict__ keep) {
  __shared__ int flag;
  if (threadIdx.x == 0) flag = 0;
  __syncthreads();
  int j = blockIdx.x;
  int m = 0;
  for (int t = threadIdx.x; t < 1024; t += 256)
    m |= (qhs[j * 1024 + t] == kh[j * 1024 + t]);
  if (m) flag = 1;
  __syncthreads();
  if (threadIdx.x == 0) keep[j] = flag;
}

// ---------------------------------------------------------------------------
// 4) K -> bf16 [B,H,N,D] with keep-zeroing (keep[h*4 + ki/512], batch-shared)
// ---------------------------------------------------------------------------
__global__ void convert_k_kernel(const float* __restrict__ k, const int* __restrict__ keep,
                                 unsigned short* __restrict__ Kc) {
  long long gid = (long long)blockIdx.x * 256 + threadIdx.x;
  int row = (int)(gid >> 5);
  int dg = (int)(gid & 31) * 4;
  int bh = row >> 11, ki = row & 2047;
  int b = bh >> 4, h = bh & 15;
  int kp = keep[h * 4 + (ki >> 9)];
  ushort4 y;
  if (kp) {
    float4 x = *(const float4*)(k + (((long long)(b * NN + ki) * HH + h) << 7) + dg);
    y = make_ushort4(f2bf(x.x), f2bf(x.y), f2bf(x.z), f2bf(x.w));
  } else {
    y = make_ushort4(0, 0, 0, 0);
  }
  *(ushort4*)(Kc + (long long)row * DD + dg) = y;
}

// ---------------------------------------------------------------------------
// 5) Flash attention over sorted Q, load-balanced pairing.
//    Grid (16,32). Block bx handles q-tile A=bx (light) and q-tile B=31-bx
//    (heavy). Wave w: qg0 = A rows [w*16,w*16+16), qg1 = B rows same. One
//    shared K-loop kb=0..31-bx; qg0 active while kb<=bx -> every wave does
//    exactly 33 qg-tile units (perfect balance, all 512 blocks co-resident).
//    K/V MFMA fragments loaded directly from global (dense 1KB/instr, L1/L2
//    reuse across the 4 waves); LDS only for per-wave P C->A transpose.
// ---------------------------------------------------------------------------
__global__ __launch_bounds__(256, 2) void flash_kernel(
    const float* __restrict__ q, const unsigned short* __restrict__ Kc,
    const unsigned short* __restrict__ Vt, const int* __restrict__ sidx,
    float* __restrict__ out) {
  __shared__ __align__(16) unsigned short Pb[4][2][16 * 72];

  int bx = blockIdx.x;              // 0..15
  int bh = blockIdx.y;
  int b = bh >> 4, h = bh & 15;
  int tid = threadIdx.x;
  int w = tid >> 6, lane = tid & 63;
  int l16 = lane & 15, qd = lane >> 4;
  int tA = bx, tB = 31 - bx;
  int qrow0 = tA * 64 + w * 16 + l16;
  int qrow1 = tB * 64 + w * 16 + l16;

  // Q fragments for both groups, gathered from fp32 q via sidx (once per wave)
  bf16x8 qf0[4], qf1[4];
  {
    int n0 = sidx[bh * NN + qrow0];
    int n1 = sidx[bh * NN + qrow1];
    const float* p0 = q + (((long long)(b * NN + n0) * HH + h) << 7) + qd * 8;
    const float* p1 = q + (((long long)(b * NN + n1) * HH + h) << 7) + qd * 8;
#pragma unroll
    for (int c = 0; c < 4; ++c) {
      qf0[c] = load_q8(p0 + c * 32);
      qf1[c] = load_q8(p1 + c * 32);
    }
  }
  f32x4 o0[8], o1[8];
#pragma unroll
  for (int i = 0; i < 8; ++i) {
    o0[i] = (f32x4){0.f, 0.f, 0.f, 0.f};
    o1[i] = (f32x4){0.f, 0.f, 0.f, 0.f};
  }
  float m0 = -__builtin_inff(), l0 = 0.f;
  float m1 = -__builtin_inff(), l1 = 0.f;
  const float scale = 0.088388347648318447f;  // 128^-0.5

  const unsigned short* Kb = Kc + (long long)bh * NN * DD;
  const unsigned short* Vb = Vt + (long long)bh * DD * NN;

  for (int kb = 0; kb <= tB; ++kb) {
    int k0 = kb * 64;
    bool act0 = (kb <= tA);   // block-uniform
    float s0[16], s1[16];

    // --- S^T = K * Q^T (K fragments shared by both q-groups) ---
#pragma unroll
    for (int t = 0; t < 4; ++t) {
      bf16x8 kf[4];
      const unsigned short* kr = Kb + (long long)(k0 + t * 16 + l16) * DD + qd * 8;
#pragma unroll
      for (int c = 0; c < 4; ++c) kf[c] = *(const bf16x8*)(kr + c * 32);
      f32x4 a1 = (f32x4){0.f, 0.f, 0.f, 0.f};
#pragma unroll
      for (int c = 0; c < 4; ++c)
        a1 = __builtin_amdgcn_mfma_f32_16x16x32_bf16(kf[c], qf1[c], a1, 0, 0, 0);
#pragma unroll
      for (int r = 0; r < 4; ++r) {
        int keyg = k0 + t * 16 + qd * 4 + r;
        s1[t * 4 + r] = (keyg > qrow1) ? -__builtin_inff() : a1[r] * scale;
      }
      if (act0) {
        f32x4 a0 = (f32x4){0.f, 0.f, 0.f, 0.f};
#pragma unroll
        for (int c = 0; c < 4; ++c)
          a0 = __builtin_amdgcn_mfma_f32_16x16x32_bf16(kf[c], qf0[c], a0, 0, 0, 0);
#pragma unroll
        for (int r = 0; r < 4; ++r) {
          int keyg = k0 + t * 16 + qd * 4 + r;
          s0[t * 4 + r] = (keyg > qrow0) ? -__builtin_inff() : a0[r] * scale;
        }
      }
    }

    // --- online softmax, group 1 (always active) ---
    {
      float mloc = s1[0];
#pragma unroll
      for (int i = 1; i < 16; ++i) mloc = fmaxf(mloc, s1[i]);
      mloc = fmaxf(mloc, __shfl_xor(mloc, 16));
      mloc = fmaxf(mloc, __shfl_xor(mloc, 32));
      float mnew = fmaxf(m1, mloc);
      float alpha = __expf(m1 - mnew);
      float psum = 0.f;
#pragma unroll
      for (int t = 0; t < 4; ++t) {
        float p0 = __expf(s1[t * 4 + 0] - mnew);
        float p1 = __expf(s1[t * 4 + 1] - mnew);
        float p2 = __expf(s1[t * 4 + 2] - mnew);
        float p3 = __expf(s1[t * 4 + 3] - mnew);
        psum += (p0 + p1) + (p2 + p3);
        *(ushort4*)&Pb[w][1][l16 * 72 + t * 16 + qd * 4] =
            make_ushort4(f2bf(p0), f2bf(p1), f2bf(p2), f2bf(p3));
      }
      psum += __shfl_xor(psum, 16);
      psum += __shfl_xor(psum, 32);
      l1 = l1 * alpha + psum;
      m1 = mnew;
      float aO[4];
#pragma unroll
      for (int r = 0; r < 4; ++r) aO[r] = __shfl(alpha, qd * 4 + r);
#pragma unroll
      for (int c8 = 0; c8 < 8; ++c8)
#pragma unroll
        for (int r = 0; r < 4; ++r) o1[c8][r] *= aO[r];
    }
    // --- online softmax, group 0 ---
    if (act0) {
      float mloc = s0[0];
#pragma unroll
      for (int i = 1; i < 16; ++i) mloc = fmaxf(mloc, s0[i]);
      mloc = fmaxf(mloc, __shfl_xor(mloc, 16));
      mloc = fmaxf(mloc, __shfl_xor(mloc, 32));
      float mnew = fmaxf(m0, mloc);
      float alpha = __expf(m0 - mnew);
      float psum = 0.f;
#pragma unroll
      for (int t = 0; t < 4; ++t) {
        float p0 = __expf(s0[t * 4 + 0] - mnew);
        float p1 = __expf(s0[t * 4 + 1] - mnew);
        float p2 = __expf(s0[t * 4 + 2] - mnew);
        float p3 = __expf(s0[t * 4 + 3] - mnew);
        psum += (p0 + p1) + (p2 + p3);
        *(ushort4*)&Pb[w][0][l16 * 72 + t * 16 + qd * 4] =
            make_ushort4(f2bf(p0), f2bf(p1), f2bf(p2), f2bf(p3));
      }
      psum += __shfl_xor(psum, 16);
      psum += __shfl_xor(psum, 32);
      l0 = l0 * alpha + psum;
      m0 = mnew;
      float aO[4];
#pragma unroll
      for (int r = 0; r < 4; ++r) aO[r] = __shfl(alpha, qd * 4 + r);
#pragma unroll
      for (int c8 = 0; c8 < 8; ++c8)
#pragma unroll
        for (int r = 0; r < 4; ++r) o0[c8][r] *= aO[r];
    }

    // --- O += P * V  (V fragments shared by both q-groups) ---
#pragma unroll
    for (int g = 0; g < 2; ++g) {
      bf16x8 pf1 = *(const bf16x8*)&Pb[w][1][l16 * 72 + g * 32 + qd * 8];
      bf16x8 pf0;
      if (act0) pf0 = *(const bf16x8*)&Pb[w][0][l16 * 72 + g * 32 + qd * 8];
      const unsigned short* vr = Vb + (long long)l16 * NN + k0 + g * 32 + qd * 8;
#pragma unroll
      for (int c8 = 0; c8 < 8; ++c8) {
        bf16x8 vf = *(const bf16x8*)(vr + (long long)c8 * 16 * NN);
        o1[c8] = __builtin_amdgcn_mfma_f32_16x16x32_bf16(pf1, vf, o1[c8], 0, 0, 0);
        if (act0)
          o0[c8] = __builtin_amdgcn_mfma_f32_16x16x32_bf16(pf0, vf, o0[c8], 0, 0, 0);
      }
    }
    __syncthreads();  // keep the block's 4 waves on the same tile (L1 locality)
  }

  // --- epilogue: normalize and scatter-unsort, both q-groups ---
#pragma unroll
  for (int qg = 0; qg < 2; ++qg) {
    float lg = qg ? l1 : l0;
    int qtile = qg ? tB : tA;
    float lO[4];
    int nO[4];
#pragma unroll
    for (int r = 0; r < 4; ++r) {
      lO[r] = __shfl(lg, qd * 4 + r);
      nO[r] = sidx[(long long)bh * NN + qtile * 64 + w * 16 + qd * 4 + r];
    }
#pragma unroll
    for (int r = 0; r < 4; ++r) {
      float inv = 1.f / lO[r];
      float* ob = out + (((long long)(b * NN + nO[r]) * HH + h) << 7) + l16;
#pragma unroll
      for (int c8 = 0; c8 < 8; ++c8)
        ob[c8 * 16] = (qg ? o1[c8][r] : o0[c8][r]) * inv;
    }
  }
}

// ---------------------------------------------------------------------------
// Workspace layout (bytes):
//   0        : q_hash   [B,H,N] int   (256 KiB)
//   256 KiB  : k_hash                 (256 KiB)
//   512 KiB  : sort_idx               (256 KiB)
//   768 KiB  : q_hash_sort            (256 KiB)
//   1 MiB    : keep[64] int
//   2 MiB    : Kc bf16 [B,H,N,D]      (16 MiB)
//   18 MiB   : Vt bf16 [B,H,D,N]      (16 MiB)   total 34 MiB
// ---------------------------------------------------------------------------
extern "C" void kernel_launch(void* const* d_in, const int* in_sizes, int n_in,
                              void* d_out, int out_size, void* d_ws, size_t ws_size,
                              hipStream_t stream) {
  const float* q = (const float*)d_in[0];
  const float* k = (const float*)d_in[1];
  const float* v = (const float*)d_in[2];
  const float* pd = (const float*)d_in[3];
  float* out = (float*)d_out;
  char* ws = (char*)d_ws;
  int* qh   = (int*)(ws + 0);
  int* kh   = (int*)(ws + (1u << 18));
  int* sidx = (int*)(ws + (2u << 18));
  int* qhs  = (int*)(ws + 3u * (1u << 18));
  int* keep = (int*)(ws + (1u << 20));
  unsigned short* Kc = (unsigned short*)(ws + (2u << 20));
  unsigned short* Vt = (unsigned short*)(ws + (18u << 20));

  prep_kernel<<<5120, 256, 0, stream>>>(q, k, v, pd, qh, kh, Vt);
  sort_kernel<<<32, 512, 0, stream>>>(qh, sidx, qhs);
  keep_kernel<<<64, 256, 0, stream>>>(qhs, kh, keep);
  convert_k_kernel<<<8192, 256, 0, stream>>>(k, keep, Kc);
  flash_kernel<<<dim3(16, 32), 256, 0, stream>>>(q, Kc, Vt, sidx, out);
}

// Round 3
// 1202.661 us; speedup vs baseline: 1.4214x; 1.4214x over previous
//
#include <hip/hip_runtime.h>
#include <cstdint>

// Problem constants (B,N,H,D fixed by setup_inputs)
#define BB 2
#define NN 2048
#define HH 16
#define DD 128
#define BH 32   // BB*HH
#define NPROJ 7

typedef __bf16 bf16x8 __attribute__((ext_vector_type(8)));
typedef float f32x4 __attribute__((ext_vector_type(4)));

__device__ __forceinline__ unsigned short f2bf(float f) {
  unsigned int u = __float_as_uint(f);
  u += 0x7fff + ((u >> 16) & 1);   // RN-even
  return (unsigned short)(u >> 16);
}

__device__ __forceinline__ bf16x8 load_q8(const float* p) {
  float4 a = *(const float4*)p;
  float4 b = *(const float4*)(p + 4);
  unsigned short r[8] = {f2bf(a.x), f2bf(a.y), f2bf(a.z), f2bf(a.w),
                         f2bf(b.x), f2bf(b.y), f2bf(b.z), f2bf(b.w)};
  return *(bf16x8*)r;
}

// ---------------------------------------------------------------------------
// 1) Fused: LSH hash of q and k rows (blocks < 4096) + V bf16 transpose to
//    [B,H,D,N] (blocks >= 4096). Hash: 8 lanes per row, fp64 accumulation.
// ---------------------------------------------------------------------------
__global__ void prep_kernel(const float* __restrict__ q, const float* __restrict__ k,
                            const float* __restrict__ v, const float* __restrict__ pd,
                            int* __restrict__ qh, int* __restrict__ kh,
                            unsigned short* __restrict__ Vt) {
  __shared__ __align__(16) char smem[64 * 132 * 2];  // union: spd (3.5K) / tile (16.5K)
  if (blockIdx.x < 4096) {
    float* spd = (float*)smem;
    for (int i = threadIdx.x; i < DD * NPROJ; i += 256) spd[i] = pd[i];
    __syncthreads();
    long long gid = (long long)blockIdx.x * 256 + threadIdx.x;
    int part = (int)(gid & 7);
    long long row = gid >> 3;
    const long long NR = (long long)BB * NN * HH;
    int isk = row >= NR;
    long long r = isk ? row - NR : row;            // flat [b][n][h]
    const float* src = (isk ? k : q) + r * DD + part * 16;
    double acc[NPROJ];
    for (int p = 0; p < NPROJ; ++p) acc[p] = 0.0;
    for (int d = 0; d < 16; d += 4) {
      float4 x = *(const float4*)(src + d);
      int dbase = part * 16 + d;
      for (int p = 0; p < NPROJ; ++p) {
        acc[p] += (double)x.x * (double)spd[(dbase + 0) * NPROJ + p]
                + (double)x.y * (double)spd[(dbase + 1) * NPROJ + p]
                + (double)x.z * (double)spd[(dbase + 2) * NPROJ + p]
                + (double)x.w * (double)spd[(dbase + 3) * NPROJ + p];
      }
    }
    for (int off = 1; off < 8; off <<= 1)
      for (int p = 0; p < NPROJ; ++p) acc[p] += __shfl_xor(acc[p], off);
    if (part == 0) {
      int bin = 0;
      for (int p = 0; p < NPROJ; ++p) bin |= ((int)(acc[p] > 0.0)) << p;
      int hsh = bin ^ (bin >> 1);                  // _unit_hamming == Gray code
      int b_ = (int)(r / (NN * HH));
      int rem = (int)(r % (NN * HH));
      int n_ = rem / HH, h_ = rem % HH;
      (isk ? kh : qh)[((long long)b_ * HH + h_) * NN + n_] = hsh;
    }
  } else {
    unsigned short (*tile)[132] = (unsigned short(*)[132])smem;
    int blk = blockIdx.x - 4096;
    int bh = blk >> 5;
    int n0 = (blk & 31) * 64;
    int b = bh >> 4, h = bh & 15;
    for (int it = 0; it < 8; ++it) {
      int cid = it * 256 + threadIdx.x;
      int r = cid >> 5, d4 = (cid & 31) * 4;
      float4 x = *(const float4*)(v + (((long long)(b * NN + n0 + r) * HH + h) << 7) + d4);
      *(ushort4*)&tile[r][d4] = make_ushort4(f2bf(x.x), f2bf(x.y), f2bf(x.z), f2bf(x.w));
    }
    __syncthreads();
    for (int it = 0; it < 8; ++it) {
      int cid = it * 256 + threadIdx.x;
      int d = cid >> 4, n4 = (cid & 15) * 4;
      ushort4 y = make_ushort4(tile[n4 + 0][d], tile[n4 + 1][d], tile[n4 + 2][d], tile[n4 + 3][d]);
      *(ushort4*)(Vt + ((long long)bh * DD + d) * NN + n0 + n4) = y;
    }
  }
}

// ---------------------------------------------------------------------------
// 2) Stable counting sort of q_hash per (b,h) + fused keep computation.
//    keep[bh*2 + half] = OR over pos in half of (q_hash_sort[pos]==k_hash[pos])
//    (flat [B,H,N]/1024 windows, exactly the reference reshape semantics).
// ---------------------------------------------------------------------------
__global__ void sortkeep_kernel(const int* __restrict__ qh, const int* __restrict__ kh,
                                int* __restrict__ sidx, int* __restrict__ keep) {
  __shared__ int sh[NN];
  __shared__ int cnt[4][128];
  __shared__ int cum[128];
  __shared__ int kflag[2];
  int bh = blockIdx.x;
  const int* src = qh + (long long)bh * NN;
  for (int i = threadIdx.x; i < NN; i += 512) sh[i] = src[i];
  if (threadIdx.x < 2) kflag[threadIdx.x] = 0;
  __syncthreads();
  int bin = threadIdx.x & 127, seg = threadIdx.x >> 7;
  int n0 = seg * (NN / 4);
  int c = 0;
  for (int n = n0; n < n0 + NN / 4; ++n) c += (sh[n] == bin);
  cnt[seg][bin] = c;
  __syncthreads();
  if (threadIdx.x == 0) {
    int run = 0;
    for (int t = 0; t < 128; ++t) {
      cum[t] = run;
      run += cnt[0][t] + cnt[1][t] + cnt[2][t] + cnt[3][t];
    }
  }
  __syncthreads();
  int pos = cum[bin];
  for (int s = 0; s < seg; ++s) pos += cnt[s][bin];
  int f0 = 0, f1 = 0;
  for (int n = n0; n < n0 + NN / 4; ++n)
    if (sh[n] == bin) {
      sidx[(long long)bh * NN + pos] = n;
      int match = (bin == kh[(long long)bh * NN + pos]);
      if (pos < 1024) f0 |= match; else f1 |= match;
      ++pos;
    }
  if (f0) atomicOr(&kflag[0], 1);
  if (f1) atomicOr(&kflag[1], 1);
  __syncthreads();
  if (threadIdx.x < 2) keep[bh * 2 + threadIdx.x] = kflag[threadIdx.x];
}

// ---------------------------------------------------------------------------
// 3) Flash attention over sorted Q, load-balanced pairing + LDS staging.
//    Grid (16,32). Block bx handles q-tiles A=bx (light) and B=31-bx (heavy);
//    one shared K-loop kb=0..31-bx, group A active while kb<=bx -> every wave
//    does exactly 33 q-tile units; 512 blocks = exactly 2/CU, all resident.
//    K staged fp32->bf16 from global with keep-zeroing (replaces convert_k),
//    V staged from pre-transposed Vt. K/V LDS fragments feed BOTH q-groups.
//    amdgpu_waves_per_eu(2,2): 256-VGPR budget -> no scratch spills (R2 bug).
// ---------------------------------------------------------------------------
__global__ __launch_bounds__(256) __attribute__((amdgpu_waves_per_eu(2, 2)))
void flash_kernel(const float* __restrict__ q, const float* __restrict__ k,
                  const unsigned short* __restrict__ Vt, const int* __restrict__ sidx,
                  const int* __restrict__ keep, float* __restrict__ out) {
  __shared__ __align__(16) unsigned short Kt[64 * 136];   // keys x d (+8 pad)
  __shared__ __align__(16) unsigned short Vs[128 * 72];   // d x keys (+8 pad)
  __shared__ __align__(16) unsigned short Pb[4][2][16 * 72];

  int bx = blockIdx.x;              // 0..15
  int bh = blockIdx.y;
  int b = bh >> 4, h = bh & 15;
  int tid = threadIdx.x;
  int w = tid >> 6, lane = tid & 63;
  int l16 = lane & 15, qd = lane >> 4;
  int tA = bx, tB = 31 - bx;
  int qrow0 = tA * 64 + w * 16 + l16;
  int qrow1 = tB * 64 + w * 16 + l16;

  const float* kbase = k + (long long)b * NN * HH * DD + h * DD;
  const unsigned short* Vb = Vt + (long long)bh * DD * NN;

  // Q fragments for both groups, gathered from fp32 q via sidx (once per wave)
  bf16x8 qf0[4], qf1[4];
  {
    int n0 = sidx[bh * NN + qrow0];
    int n1 = sidx[bh * NN + qrow1];
    const float* p0 = q + (((long long)(b * NN + n0) * HH + h) << 7) + qd * 8;
    const float* p1 = q + (((long long)(b * NN + n1) * HH + h) << 7) + qd * 8;
#pragma unroll
    for (int c = 0; c < 4; ++c) {
      qf0[c] = load_q8(p0 + c * 32);
      qf1[c] = load_q8(p1 + c * 32);
    }
  }
  f32x4 o0[8], o1[8];
#pragma unroll
  for (int i = 0; i < 8; ++i) {
    o0[i] = (f32x4){0.f, 0.f, 0.f, 0.f};
    o1[i] = (f32x4){0.f, 0.f, 0.f, 0.f};
  }
  float m0 = -__builtin_inff(), l0 = 0.f;
  float m1 = -__builtin_inff(), l1 = 0.f;
  const float scale = 0.088388347648318447f;  // 128^-0.5

  for (int kb = 0; kb <= tB; ++kb) {
    int k0 = kb * 64;
    bool act0 = (kb <= tA);   // block-uniform
    int kp = keep[h * 4 + (k0 >> 9)];

    // --- stage K (fp32 -> bf16, keep-zeroed) and V into LDS ---
    if (kp) {
#pragma unroll
      for (int it = 0; it < 8; ++it) {
        int cid = it * 256 + tid;
        int r = cid >> 5, d4 = (cid & 31) * 4;
        float4 x = *(const float4*)(kbase + (long long)(k0 + r) * (HH * DD) + d4);
        *(ushort4*)&Kt[r * 136 + d4] = make_ushort4(f2bf(x.x), f2bf(x.y), f2bf(x.z), f2bf(x.w));
      }
    } else {
#pragma unroll
      for (int it = 0; it < 8; ++it) {
        int cid = it * 256 + tid;
        int r = cid >> 5, d4 = (cid & 31) * 4;
        *(ushort4*)&Kt[r * 136 + d4] = make_ushort4(0, 0, 0, 0);
      }
    }
#pragma unroll
    for (int it = 0; it < 4; ++it) {
      int cid = it * 256 + tid;
      int r = cid >> 3, c8 = (cid & 7) * 8;
      *(uint4*)&Vs[r * 72 + c8] = *(const uint4*)(Vb + (long long)r * NN + k0 + c8);
    }
    __syncthreads();

    // --- S^T = K * Q^T (K fragments from LDS, shared by both q-groups) ---
    float s0[16], s1[16];
#pragma unroll
    for (int t = 0; t < 4; ++t) {
      bf16x8 kf[4];
#pragma unroll
      for (int c = 0; c < 4; ++c)
        kf[c] = *(const bf16x8*)&Kt[(t * 16 + l16) * 136 + c * 32 + qd * 8];
      f32x4 a1 = (f32x4){0.f, 0.f, 0.f, 0.f};
#pragma unroll
      for (int c = 0; c < 4; ++c)
        a1 = __builtin_amdgcn_mfma_f32_16x16x32_bf16(kf[c], qf1[c], a1, 0, 0, 0);
#pragma unroll
      for (int r = 0; r < 4; ++r) {
        int keyg = k0 + t * 16 + qd * 4 + r;
        s1[t * 4 + r] = (keyg > qrow1) ? -__builtin_inff() : a1[r] * scale;
      }
      if (act0) {
        f32x4 a0 = (f32x4){0.f, 0.f, 0.f, 0.f};
#pragma unroll
        for (int c = 0; c < 4; ++c)
          a0 = __builtin_amdgcn_mfma_f32_16x16x32_bf16(kf[c], qf0[c], a0, 0, 0, 0);
#pragma unroll
        for (int r = 0; r < 4; ++r) {
          int keyg = k0 + t * 16 + qd * 4 + r;
          s0[t * 4 + r] = (keyg > qrow0) ? -__builtin_inff() : a0[r] * scale;
        }
      }
    }

    // --- online softmax, group 1 (always active) ---
    {
      float mloc = s1[0];
#pragma unroll
      for (int i = 1; i < 16; ++i) mloc = fmaxf(mloc, s1[i]);
      mloc = fmaxf(mloc, __shfl_xor(mloc, 16));
      mloc = fmaxf(mloc, __shfl_xor(mloc, 32));
      float mnew = fmaxf(m1, mloc);
      float alpha = __expf(m1 - mnew);
      float psum = 0.f;
#pragma unroll
      for (int t = 0; t < 4; ++t) {
        float p0 = __expf(s1[t * 4 + 0] - mnew);
        float p1 = __expf(s1[t * 4 + 1] - mnew);
        float p2 = __expf(s1[t * 4 + 2] - mnew);
        float p3 = __expf(s1[t * 4 + 3] - mnew);
        psum += (p0 + p1) + (p2 + p3);
        *(ushort4*)&Pb[w][1][l16 * 72 + t * 16 + qd * 4] =
            make_ushort4(f2bf(p0), f2bf(p1), f2bf(p2), f2bf(p3));
      }
      psum += __shfl_xor(psum, 16);
      psum += __shfl_xor(psum, 32);
      l1 = l1 * alpha + psum;
      m1 = mnew;
      float aO[4];
#pragma unroll
      for (int r = 0; r < 4; ++r) aO[r] = __shfl(alpha, qd * 4 + r);
#pragma unroll
      for (int c8 = 0; c8 < 8; ++c8)
#pragma unroll
        for (int r = 0; r < 4; ++r) o1[c8][r] *= aO[r];
    }
    // --- online softmax, group 0 ---
    if (act0) {
      float mloc = s0[0];
#pragma unroll
      for (int i = 1; i < 16; ++i) mloc = fmaxf(mloc, s0[i]);
      mloc = fmaxf(mloc, __shfl_xor(mloc, 16));
      mloc = fmaxf(mloc, __shfl_xor(mloc, 32));
      float mnew = fmaxf(m0, mloc);
      float alpha = __expf(m0 - mnew);
      float psum = 0.f;
#pragma unroll
      for (int t = 0; t < 4; ++t) {
        float p0 = __expf(s0[t * 4 + 0] - mnew);
        float p1 = __expf(s0[t * 4 + 1] - mnew);
        float p2 = __expf(s0[t * 4 + 2] - mnew);
        float p3 = __expf(s0[t * 4 + 3] - mnew);
        psum += (p0 + p1) + (p2 + p3);
        *(ushort4*)&Pb[w][0][l16 * 72 + t * 16 + qd * 4] =
            make_ushort4(f2bf(p0), f2bf(p1), f2bf(p2), f2bf(p3));
      }
      psum += __shfl_xor(psum, 16);
      psum += __shfl_xor(psum, 32);
      l0 = l0 * alpha + psum;
      m0 = mnew;
      float aO[4];
#pragma unroll
      for (int r = 0; r < 4; ++r) aO[r] = __shfl(alpha, qd * 4 + r);
#pragma unroll
      for (int c8 = 0; c8 < 8; ++c8)
#pragma unroll
        for (int r = 0; r < 4; ++r) o0[c8][r] *= aO[r];
    }

    // --- O += P * V  (V fragments from LDS, shared by both q-groups) ---
#pragma unroll
    for (int g = 0; g < 2; ++g) {
      bf16x8 pf1 = *(const bf16x8*)&Pb[w][1][l16 * 72 + g * 32 + qd * 8];
      bf16x8 pf0;
      if (act0) pf0 = *(const bf16x8*)&Pb[w][0][l16 * 72 + g * 32 + qd * 8];
#pragma unroll
      for (int c8 = 0; c8 < 8; ++c8) {
        bf16x8 vf = *(const bf16x8*)&Vs[(c8 * 16 + l16) * 72 + g * 32 + qd * 8];
        o1[c8] = __builtin_amdgcn_mfma_f32_16x16x32_bf16(pf1, vf, o1[c8], 0, 0, 0);
        if (act0)
          o0[c8] = __builtin_amdgcn_mfma_f32_16x16x32_bf16(pf0, vf, o0[c8], 0, 0, 0);
      }
    }
    __syncthreads();
  }

  // --- epilogue: normalize and scatter-unsort, both q-groups ---
#pragma unroll
  for (int qg = 0; qg < 2; ++qg) {
    float lg = qg ? l1 : l0;
    int qtile = qg ? tB : tA;
    float lO[4];
    int nO[4];
#pragma unroll
    for (int r = 0; r < 4; ++r) {
      lO[r] = __shfl(lg, qd * 4 + r);
      nO[r] = sidx[(long long)bh * NN + qtile * 64 + w * 16 + qd * 4 + r];
    }
#pragma unroll
    for (int r = 0; r < 4; ++r) {
      float inv = 1.f / lO[r];
      float* ob = out + (((long long)(b * NN + nO[r]) * HH + h) << 7) + l16;
#pragma unroll
      for (int c8 = 0; c8 < 8; ++c8)
        ob[c8 * 16] = (qg ? o1[c8][r] : o0[c8][r]) * inv;
    }
  }
}

// ---------------------------------------------------------------------------
// Workspace layout (bytes):
//   0        : q_hash   [B,H,N] int   (256 KiB)
//   256 KiB  : k_hash                 (256 KiB)
//   512 KiB  : sort_idx               (256 KiB)
//   768 KiB  : keep[64] int
//   2 MiB    : Vt bf16 [B,H,D,N]      (16 MiB)   total 18 MiB
// ---------------------------------------------------------------------------
extern "C" void kernel_launch(void* const* d_in, const int* in_sizes, int n_in,
                              void* d_out, int out_size, void* d_ws, size_t ws_size,
                              hipStream_t stream) {
  const float* q = (const float*)d_in[0];
  const float* k = (const float*)d_in[1];
  const float* v = (const float*)d_in[2];
  const float* pd = (const float*)d_in[3];
  float* out = (float*)d_out;
  char* ws = (char*)d_ws;
  int* qh   = (int*)(ws + 0);
  int* kh   = (int*)(ws + (1u << 18));
  int* sidx = (int*)(ws + (2u << 18));
  int* keep = (int*)(ws + 3u * (1u << 18));
  unsigned short* Vt = (unsigned short*)(ws + (2u << 20));

  prep_kernel<<<5120, 256, 0, stream>>>(q, k, v, pd, qh, kh, Vt);
  sortkeep_kernel<<<32, 512, 0, stream>>>(qh, kh, sidx, keep);
  flash_kernel<<<dim3(16, 32), 256, 0, stream>>>(q, k, Vt, sidx, keep, out);
}

// Round 4
// 363.143 us; speedup vs baseline: 4.7075x; 3.3118x over previous
//
#include <hip/hip_runtime.h>
#include <cstdint>

// Problem constants (B,N,H,D fixed by setup_inputs)
#define BB 2
#define NN 2048
#define HH 16
#define DD 128
#define BH 32   // BB*HH
#define NPROJ 7

typedef __bf16 bf16x8 __attribute__((ext_vector_type(8)));
typedef float f32x4 __attribute__((ext_vector_type(4)));

__device__ __forceinline__ unsigned short f2bf(float f) {
  unsigned int u = __float_as_uint(f);
  u += 0x7fff + ((u >> 16) & 1);   // RN-even
  return (unsigned short)(u >> 16);
}

__device__ __forceinline__ bf16x8 load_q8(const float* p) {
  float4 a = *(const float4*)p;
  float4 b = *(const float4*)(p + 4);
  unsigned short r[8] = {f2bf(a.x), f2bf(a.y), f2bf(a.z), f2bf(a.w),
                         f2bf(b.x), f2bf(b.y), f2bf(b.z), f2bf(b.w)};
  return *(bf16x8*)r;
}

// ---------------------------------------------------------------------------
// 1) Fused: LSH hash of q and k rows (blocks < 4096) + V bf16 transpose to
//    [B,H,D,N] (blocks >= 4096). Hash: 8 lanes per row, fp64 accumulation.
// ---------------------------------------------------------------------------
__global__ void prep_kernel(const float* __restrict__ q, const float* __restrict__ k,
                            const float* __restrict__ v, const float* __restrict__ pd,
                            int* __restrict__ qh, int* __restrict__ kh,
                            unsigned short* __restrict__ Vt) {
  __shared__ __align__(16) char smem[64 * 132 * 2];  // union: spd (3.5K) / tile (16.5K)
  if (blockIdx.x < 4096) {
    float* spd = (float*)smem;
    for (int i = threadIdx.x; i < DD * NPROJ; i += 256) spd[i] = pd[i];
    __syncthreads();
    long long gid = (long long)blockIdx.x * 256 + threadIdx.x;
    int part = (int)(gid & 7);
    long long row = gid >> 3;
    const long long NR = (long long)BB * NN * HH;
    int isk = row >= NR;
    long long r = isk ? row - NR : row;            // flat [b][n][h]
    const float* src = (isk ? k : q) + r * DD + part * 16;
    double acc[NPROJ];
    for (int p = 0; p < NPROJ; ++p) acc[p] = 0.0;
    for (int d = 0; d < 16; d += 4) {
      float4 x = *(const float4*)(src + d);
      int dbase = part * 16 + d;
      for (int p = 0; p < NPROJ; ++p) {
        acc[p] += (double)x.x * (double)spd[(dbase + 0) * NPROJ + p]
                + (double)x.y * (double)spd[(dbase + 1) * NPROJ + p]
                + (double)x.z * (double)spd[(dbase + 2) * NPROJ + p]
                + (double)x.w * (double)spd[(dbase + 3) * NPROJ + p];
      }
    }
    for (int off = 1; off < 8; off <<= 1)
      for (int p = 0; p < NPROJ; ++p) acc[p] += __shfl_xor(acc[p], off);
    if (part == 0) {
      int bin = 0;
      for (int p = 0; p < NPROJ; ++p) bin |= ((int)(acc[p] > 0.0)) << p;
      int hsh = bin ^ (bin >> 1);                  // _unit_hamming == Gray code
      int b_ = (int)(r / (NN * HH));
      int rem = (int)(r % (NN * HH));
      int n_ = rem / HH, h_ = rem % HH;
      (isk ? kh : qh)[((long long)b_ * HH + h_) * NN + n_] = hsh;
    }
  } else {
    unsigned short (*tile)[132] = (unsigned short(*)[132])smem;
    int blk = blockIdx.x - 4096;
    int bh = blk >> 5;
    int n0 = (blk & 31) * 64;
    int b = bh >> 4, h = bh & 15;
    for (int it = 0; it < 8; ++it) {
      int cid = it * 256 + threadIdx.x;
      int r = cid >> 5, d4 = (cid & 31) * 4;
      float4 x = *(const float4*)(v + (((long long)(b * NN + n0 + r) * HH + h) << 7) + d4);
      *(ushort4*)&tile[r][d4] = make_ushort4(f2bf(x.x), f2bf(x.y), f2bf(x.z), f2bf(x.w));
    }
    __syncthreads();
    for (int it = 0; it < 8; ++it) {
      int cid = it * 256 + threadIdx.x;
      int d = cid >> 4, n4 = (cid & 15) * 4;
      ushort4 y = make_ushort4(tile[n4 + 0][d], tile[n4 + 1][d], tile[n4 + 2][d], tile[n4 + 3][d]);
      *(ushort4*)(Vt + ((long long)bh * DD + d) * NN + n0 + n4) = y;
    }
  }
}

// ---------------------------------------------------------------------------
// 2) Stable counting sort of q_hash per (b,h) + fused keep computation.
//    keep[bh*2 + half] = OR over pos in half of (q_hash_sort[pos]==k_hash[pos])
// ---------------------------------------------------------------------------
__global__ void sortkeep_kernel(const int* __restrict__ qh, const int* __restrict__ kh,
                                int* __restrict__ sidx, int* __restrict__ keep) {
  __shared__ int sh[NN];
  __shared__ int cnt[4][128];
  __shared__ int cum[128];
  __shared__ int kflag[2];
  int bh = blockIdx.x;
  const int* src = qh + (long long)bh * NN;
  for (int i = threadIdx.x; i < NN; i += 512) sh[i] = src[i];
  if (threadIdx.x < 2) kflag[threadIdx.x] = 0;
  __syncthreads();
  int bin = threadIdx.x & 127, seg = threadIdx.x >> 7;
  int n0 = seg * (NN / 4);
  int c = 0;
  for (int n = n0; n < n0 + NN / 4; ++n) c += (sh[n] == bin);
  cnt[seg][bin] = c;
  __syncthreads();
  if (threadIdx.x == 0) {
    int run = 0;
    for (int t = 0; t < 128; ++t) {
      cum[t] = run;
      run += cnt[0][t] + cnt[1][t] + cnt[2][t] + cnt[3][t];
    }
  }
  __syncthreads();
  int pos = cum[bin];
  for (int s = 0; s < seg; ++s) pos += cnt[s][bin];
  int f0 = 0, f1 = 0;
  for (int n = n0; n < n0 + NN / 4; ++n)
    if (sh[n] == bin) {
      sidx[(long long)bh * NN + pos] = n;
      int match = (bin == kh[(long long)bh * NN + pos]);
      if (pos < 1024) f0 |= match; else f1 |= match;
      ++pos;
    }
  if (f0) atomicOr(&kflag[0], 1);
  if (f1) atomicOr(&kflag[1], 1);
  __syncthreads();
  if (threadIdx.x < 2) keep[bh * 2 + threadIdx.x] = kflag[threadIdx.x];
}

// ---------------------------------------------------------------------------
// 3) Flash attention over sorted Q, load-balanced TWO-PHASE blocks.
//    Grid (16,32). Block bx: phase 0 = q-tile 31-bx (heavy, kb 0..31-bx),
//    phase 1 = q-tile bx (light, kb 0..bx) -> exactly 33 K-iterations per
//    block, uniform across the grid; 512 blocks = exactly 2/CU co-resident.
//    Single q-group live state per phase (~120 VGPRs) -> no scratch spill
//    (R2/R3 failure mode: paired groups needed ~200 regs vs the 128 cap).
//    K staged fp32->bf16 with keep-zeroing; V from pre-transposed Vt; P
//    round-trips per-wave LDS for the C->A layout turn.
// ---------------------------------------------------------------------------
__global__ __launch_bounds__(256, 1)
void flash_kernel(const float* __restrict__ q, const float* __restrict__ k,
                  const unsigned short* __restrict__ Vt, const int* __restrict__ sidx,
                  const int* __restrict__ keep, float* __restrict__ out) {
  __shared__ __align__(16) unsigned short Kt[64 * 136];   // keys x d (+8 pad)
  __shared__ __align__(16) unsigned short Vs[128 * 72];   // d x keys (+8 pad)
  __shared__ __align__(16) unsigned short Pb[4][16 * 72]; // per-wave q x keys

  int bx = blockIdx.x;              // 0..15
  int bh = blockIdx.y;
  int b = bh >> 4, h = bh & 15;
  int tid = threadIdx.x;
  int w = tid >> 6, lane = tid & 63;
  int l16 = lane & 15, qd = lane >> 4;

  const float* kbase = k + (long long)b * NN * HH * DD + h * DD;
  const unsigned short* Vb = Vt + (long long)bh * DD * NN;
  const float scale = 0.088388347648318447f;  // 128^-0.5

  for (int ph = 0; ph < 2; ++ph) {
    int qt = ph ? bx : 31 - bx;     // heavy tile first
    int qrow = qt * 64 + w * 16 + l16;

    // Q fragments, gathered from fp32 q via sidx (once per phase)
    bf16x8 qf[4];
    {
      int nq = sidx[bh * NN + qrow];
      const float* p0 = q + (((long long)(b * NN + nq) * HH + h) << 7) + qd * 8;
#pragma unroll
      for (int c = 0; c < 4; ++c) qf[c] = load_q8(p0 + c * 32);
    }
    f32x4 o[8];
#pragma unroll
    for (int i = 0; i < 8; ++i) o[i] = (f32x4){0.f, 0.f, 0.f, 0.f};
    float m = -__builtin_inff(), l = 0.f;

    for (int kb = 0; kb <= qt; ++kb) {
      int k0 = kb * 64;
      int kp = keep[h * 4 + (k0 >> 9)];

      // --- stage K (fp32 -> bf16, keep-zeroed) and V into LDS ---
      if (kp) {
#pragma unroll
        for (int it = 0; it < 8; ++it) {
          int cid = it * 256 + tid;
          int r = cid >> 5, d4 = (cid & 31) * 4;
          float4 x = *(const float4*)(kbase + (long long)(k0 + r) * (HH * DD) + d4);
          *(ushort4*)&Kt[r * 136 + d4] = make_ushort4(f2bf(x.x), f2bf(x.y), f2bf(x.z), f2bf(x.w));
        }
      } else {
#pragma unroll
        for (int it = 0; it < 8; ++it) {
          int cid = it * 256 + tid;
          int r = cid >> 5, d4 = (cid & 31) * 4;
          *(ushort4*)&Kt[r * 136 + d4] = make_ushort4(0, 0, 0, 0);
        }
      }
#pragma unroll
      for (int it = 0; it < 4; ++it) {
        int cid = it * 256 + tid;
        int r = cid >> 3, c8 = (cid & 7) * 8;
        *(uint4*)&Vs[r * 72 + c8] = *(const uint4*)(Vb + (long long)r * NN + k0 + c8);
      }
      __syncthreads();

      // --- S^T = K * Q^T (K fragments from LDS) ---
      float s[16];
#pragma unroll
      for (int t = 0; t < 4; ++t) {
        f32x4 a1 = (f32x4){0.f, 0.f, 0.f, 0.f};
#pragma unroll
        for (int c = 0; c < 4; ++c) {
          bf16x8 kf = *(const bf16x8*)&Kt[(t * 16 + l16) * 136 + c * 32 + qd * 8];
          a1 = __builtin_amdgcn_mfma_f32_16x16x32_bf16(kf, qf[c], a1, 0, 0, 0);
        }
#pragma unroll
        for (int r = 0; r < 4; ++r) {
          int keyg = k0 + t * 16 + qd * 4 + r;
          s[t * 4 + r] = (keyg > qrow) ? -__builtin_inff() : a1[r] * scale;
        }
      }

      // --- online softmax (stats per q = lane&15, replicated across quads) ---
      {
        float mloc = s[0];
#pragma unroll
        for (int i = 1; i < 16; ++i) mloc = fmaxf(mloc, s[i]);
        mloc = fmaxf(mloc, __shfl_xor(mloc, 16));
        mloc = fmaxf(mloc, __shfl_xor(mloc, 32));
        float mnew = fmaxf(m, mloc);
        float alpha = __expf(m - mnew);
        float psum = 0.f;
#pragma unroll
        for (int t = 0; t < 4; ++t) {
          float p0 = __expf(s[t * 4 + 0] - mnew);
          float p1 = __expf(s[t * 4 + 1] - mnew);
          float p2 = __expf(s[t * 4 + 2] - mnew);
          float p3 = __expf(s[t * 4 + 3] - mnew);
          psum += (p0 + p1) + (p2 + p3);
          *(ushort4*)&Pb[w][l16 * 72 + t * 16 + qd * 4] =
              make_ushort4(f2bf(p0), f2bf(p1), f2bf(p2), f2bf(p3));
        }
        psum += __shfl_xor(psum, 16);
        psum += __shfl_xor(psum, 32);
        l = l * alpha + psum;
        m = mnew;
        float aO[4];
#pragma unroll
        for (int r = 0; r < 4; ++r) aO[r] = __shfl(alpha, qd * 4 + r);
#pragma unroll
        for (int c8 = 0; c8 < 8; ++c8)
#pragma unroll
          for (int r = 0; r < 4; ++r) o[c8][r] *= aO[r];
      }

      // --- O += P * V  (V fragments from LDS) ---
#pragma unroll
      for (int g = 0; g < 2; ++g) {
        bf16x8 pf = *(const bf16x8*)&Pb[w][l16 * 72 + g * 32 + qd * 8];
#pragma unroll
        for (int c8 = 0; c8 < 8; ++c8) {
          bf16x8 vf = *(const bf16x8*)&Vs[(c8 * 16 + l16) * 72 + g * 32 + qd * 8];
          o[c8] = __builtin_amdgcn_mfma_f32_16x16x32_bf16(pf, vf, o[c8], 0, 0, 0);
        }
      }
      __syncthreads();
    }

    // --- epilogue: normalize and scatter-unsort (no LDS access) ---
    float lO[4];
    int nO[4];
#pragma unroll
    for (int r = 0; r < 4; ++r) {
      lO[r] = __shfl(l, qd * 4 + r);
      nO[r] = sidx[(long long)bh * NN + qt * 64 + w * 16 + qd * 4 + r];
    }
#pragma unroll
    for (int r = 0; r < 4; ++r) {
      float inv = 1.f / lO[r];
      float* ob = out + (((long long)(b * NN + nO[r]) * HH + h) << 7) + l16;
#pragma unroll
      for (int c8 = 0; c8 < 8; ++c8)
        ob[c8 * 16] = o[c8][r] * inv;
    }
  }
}

// ---------------------------------------------------------------------------
// Workspace layout (bytes):
//   0        : q_hash   [B,H,N] int   (256 KiB)
//   256 KiB  : k_hash                 (256 KiB)
//   512 KiB  : sort_idx               (256 KiB)
//   768 KiB  : keep[64] int
//   2 MiB    : Vt bf16 [B,H,D,N]      (16 MiB)   total 18 MiB
// ---------------------------------------------------------------------------
extern "C" void kernel_launch(void* const* d_in, const int* in_sizes, int n_in,
                              void* d_out, int out_size, void* d_ws, size_t ws_size,
                              hipStream_t stream) {
  const float* q = (const float*)d_in[0];
  const float* k = (const float*)d_in[1];
  const float* v = (const float*)d_in[2];
  const float* pd = (const float*)d_in[3];
  float* out = (float*)d_out;
  char* ws = (char*)d_ws;
  int* qh   = (int*)(ws + 0);
  int* kh   = (int*)(ws + (1u << 18));
  int* sidx = (int*)(ws + (2u << 18));
  int* keep = (int*)(ws + 3u * (1u << 18));
  unsigned short* Vt = (unsigned short*)(ws + (2u << 20));

  prep_kernel<<<5120, 256, 0, stream>>>(q, k, v, pd, qh, kh, Vt);
  sortkeep_kernel<<<32, 512, 0, stream>>>(qh, kh, sidx, keep);
  flash_kernel<<<dim3(16, 32), 256, 0, stream>>>(q, k, Vt, sidx, keep, out);
}